// Round 3
// baseline (1228.341 us; speedup 1.0000x reference)
//
#include <hip/hip_runtime.h>
#include <math.h>

#define B_    16
#define H_    16
#define N_    4096
#define T_    8
#define DS_   256
#define DID_  128
#define L_    8
#define K_    32
#define DHID_ 1024
#define DSTEER_ 896
#define QH_   512
#define QO_   256
#define NW_   256   // B*H walkers
#define SLOTS_ 512  // chunk-slot space: 16 chunks x 32 slots
#define SCORE_SCALE 0.022097086912079608f  // 1/(8*sqrt(32))

__device__ __forceinline__ float gelu_exact(float x) {
    return 0.5f * x * (1.0f + erff(x * 0.70710678118654752f));
}

#define FMA4(c, b, a) { c.x = fmaf(b.x, (a), c.x); c.y = fmaf(b.y, (a), c.y); \
                        c.z = fmaf(b.z, (a), c.z); c.w = fmaf(b.w, (a), c.w); }

__device__ __forceinline__ void gelu4(float4& v) {
    v.x = gelu_exact(v.x); v.y = gelu_exact(v.y);
    v.z = gelu_exact(v.z); v.w = gelu_exact(v.w);
}

// acc[2 rows][4 cols] += A[2 rows][K] * B[K][4 cols]; A rows in registers
// (K-chunks of 8), B streamed as coalesced float4 (ldb-strided).
__device__ __forceinline__ void rgemm_inner(
    const float* __restrict__ a0, const float* __restrict__ a1,
    const float* __restrict__ bp, int ldb, int K,
    float4& c0, float4& c1)
{
    for (int k = 0; k < K; k += 8) {
        const float4 a0l = *reinterpret_cast<const float4*>(a0 + k);
        const float4 a0h = *reinterpret_cast<const float4*>(a0 + k + 4);
        const float4 a1l = *reinterpret_cast<const float4*>(a1 + k);
        const float4 a1h = *reinterpret_cast<const float4*>(a1 + k + 4);
        const float* b8 = bp + (size_t)k * ldb;
#define KSTEP(o, av0, av1) { float4 bv = *reinterpret_cast<const float4*>(b8 + (size_t)(o) * ldb); \
                             FMA4(c0, bv, av0); FMA4(c1, bv, av1); }
        KSTEP(0, a0l.x, a1l.x)
        KSTEP(1, a0l.y, a1l.y)
        KSTEP(2, a0l.z, a1l.z)
        KSTEP(3, a0l.w, a1l.w)
        KSTEP(4, a0h.x, a1h.x)
        KSTEP(5, a0h.y, a1h.y)
        KSTEP(6, a0h.z, a1h.z)
        KSTEP(7, a0h.w, a1h.w)
#undef KSTEP
    }
}

// out[row][j] = act(A[row][:] @ B[:, j] + bias[j]); 32 rows x 64 cols per block.
__global__ __launch_bounds__(256) void rgemm_nat_kernel(
    const float* __restrict__ A, int DIN,
    const float* __restrict__ B, int JOUT,
    const float* __restrict__ bias, float* __restrict__ out,
    int ncol, int act)
{
    int rt = blockIdx.x / ncol, ct = blockIdx.x % ncol;
    int tid = threadIdx.x;
    int tr = tid >> 4, tc = tid & 15;
    int row = rt * 32 + tr * 2;
    int col = ct * 64 + tc * 4;
    const float* a0 = A + (size_t)row * DIN;
    float4 c0 = {0.f,0.f,0.f,0.f}, c1 = {0.f,0.f,0.f,0.f};
    rgemm_inner(a0, a0 + DIN, B + col, JOUT, DIN, c0, c1);
    float4 bv = *reinterpret_cast<const float4*>(bias + col);
    c0.x += bv.x; c0.y += bv.y; c0.z += bv.z; c0.w += bv.w;
    c1.x += bv.x; c1.y += bv.y; c1.z += bv.z; c1.w += bv.w;
    if (act) { gelu4(c0); gelu4(c1); }
    *reinterpret_cast<float4*>(out + (size_t)row * JOUT + col) = c0;
    *reinterpret_cast<float4*>(out + (size_t)(row + 1) * JOUT + col) = c1;
}

// ---------------- setup kernels ----------------

__global__ __launch_bounds__(256) void init_kernel(
    const int* __restrict__ walker_pos, const int* __restrict__ plane_idx,
    int* pos, float* mp_all, int* plane_order,
    int* chunk_plane, int* chunk_rows, int* slot_of, int* nchunks_p)
{
    int tid = threadIdx.x;
    pos[tid] = walker_pos[tid];
    mp_all[tid] = 0.f;                       // 8*32 = 256
    __shared__ int cnt_s[8];
    __shared__ int cplane_s[16], cbase_s[16];
    __shared__ int nch_s;
    int wave = tid >> 6, lane = tid & 63;
    for (int pp = wave; pp < 8; pp += 4) {
        int base = 0;
        for (int c0 = 0; c0 < NW_; c0 += 64) {
            int w = c0 + lane;
            bool hit = (plane_idx[w] == pp);
            unsigned long long mask = __ballot(hit);
            if (hit) {
                int rank = __popcll(mask & ((1ull << lane) - 1ull));
                plane_order[pp * NW_ + base + rank] = w;
            }
            base += __popcll(mask);
        }
        if (lane == 0) cnt_s[pp] = base;
    }
    __syncthreads();
    if (tid == 0) {
        int nc = 0;
        for (int p = 0; p < 8; ++p)
            for (int s0 = 0; s0 < cnt_s[p]; s0 += 32) {
                cplane_s[nc] = p; cbase_s[nc] = s0; ++nc;
            }
        nch_s = nc;
        *nchunks_p = nc;
    }
    __syncthreads();
    int nc = nch_s;
    for (int idx = tid; idx < 16 * 32; idx += 256) {
        int c = idx >> 5, i = idx & 31;
        int v = -1;
        if (c < nc) {
            int p = cplane_s[c];
            int r = cbase_s[c] + i;
            if (r < cnt_s[p]) v = plane_order[p * NW_ + r];
        }
        chunk_rows[c * 32 + i] = v;
        if (v >= 0) slot_of[v] = c * 32 + i;
        if (i == 0) chunk_plane[c] = (c < nc) ? cplane_s[c] : 0;
    }
}

// ---------------- per-step kernels ----------------

__global__ __launch_bounds__(256) void steer_kernel(
    const float* __restrict__ s_out, const float* __restrict__ node_id,
    const float* __restrict__ ws_out, const float* __restrict__ token_embed,
    const float* __restrict__ norm_w, const int* __restrict__ pos,
    const int* __restrict__ slot_of,
    float* __restrict__ steer, float* __restrict__ steerT, int t)
{
    int w = blockIdx.x;
    int b = w >> 4;
    int tid = threadIdx.x;
    int p = pos[w];
    int slot = slot_of[w];
    float sc = s_out[((size_t)b * N_ + p) * DS_ + tid];
    float v = sc * sc;
    for (int off = 32; off > 0; off >>= 1) v += __shfl_down(v, off);
    __shared__ float red[4];
    if ((tid & 63) == 0) red[tid >> 6] = v;
    __syncthreads();
    float tot = red[0] + red[1] + red[2] + red[3];
    float r = rsqrtf(tot * (1.0f / DS_) + 1e-6f);
    float* st = steer + (size_t)w * DSTEER_;
    float v0 = sc * r * norm_w[tid];
    float v2 = ws_out[(size_t)w * DS_ + tid];
    float v3 = token_embed[((size_t)b * T_ + t) * DS_ + tid];
    st[tid] = v0;
    st[384 + tid] = v2;
    st[640 + tid] = v3;
    steerT[(size_t)tid * SLOTS_ + slot] = v0;
    steerT[(size_t)(384 + tid) * SLOTS_ + slot] = v2;
    steerT[(size_t)(640 + tid) * SLOTS_ + slot] = v3;
    if (tid < 128) {
        float v1 = node_id[(size_t)p * DID_ + tid];
        st[256 + tid] = v1;
        steerT[(size_t)(256 + tid) * SLOTS_ + slot] = v1;
    }
}

// blocks 0..63: q hidden (natural). blocks 64..319: content hidden -> h1T.
__global__ __launch_bounds__(256) void layer1_kernel(
    const float* __restrict__ steer, const float* __restrict__ steerT,
    const float* __restrict__ qw1, const float* __restrict__ qb1, float* __restrict__ q1,
    const float* __restrict__ W1, const float* __restrict__ b1, float* __restrict__ h1T,
    const int* __restrict__ chunk_plane, const int* __restrict__ nchunks_p)
{
    int bid = blockIdx.x;
    int tid = threadIdx.x;
    float4 c0 = {0.f,0.f,0.f,0.f}, c1 = {0.f,0.f,0.f,0.f};
    if (bid < 64) {
        int rt = bid >> 3, ct = bid & 7;
        int tr = tid >> 4, tc = tid & 15;
        int row = rt * 32 + tr * 2, col = ct * 64 + tc * 4;
        const float* a0 = steer + (size_t)row * DSTEER_;
        rgemm_inner(a0, a0 + DSTEER_, qw1 + col, QH_, DSTEER_, c0, c1);
        float4 bv = *reinterpret_cast<const float4*>(qb1 + col);
        c0.x += bv.x; c0.y += bv.y; c0.z += bv.z; c0.w += bv.w;
        c1.x += bv.x; c1.y += bv.y; c1.z += bv.z; c1.w += bv.w;
        gelu4(c0); gelu4(c1);
        *reinterpret_cast<float4*>(q1 + (size_t)row * QH_ + col) = c0;
        *reinterpret_cast<float4*>(q1 + (size_t)(row + 1) * QH_ + col) = c1;
    } else {
        int b2 = bid - 64;
        int c = b2 >> 4, jt = b2 & 15;
        if (c >= *nchunks_p) return;
        int p = chunk_plane[c];
        int tr = tid >> 3, tc = tid & 7;          // 32 x 8 threads
        int J = jt * 64 + tr * 2;
        int slot = c * 32 + tc * 4;
        const float* a0 = W1 + ((size_t)p * DHID_ + J) * DSTEER_;
        rgemm_inner(a0, a0 + DSTEER_, steerT + slot, SLOTS_, DSTEER_, c0, c1);
        float bj0 = b1[p * DHID_ + J], bj1 = b1[p * DHID_ + J + 1];
        c0.x += bj0; c0.y += bj0; c0.z += bj0; c0.w += bj0;
        c1.x += bj1; c1.y += bj1; c1.z += bj1; c1.w += bj1;
        gelu4(c0); gelu4(c1);
        *reinterpret_cast<float4*>(h1T + (size_t)J * SLOTS_ + slot) = c0;
        *reinterpret_cast<float4*>(h1T + (size_t)(J + 1) * SLOTS_ + slot) = c1;
    }
}

// blocks 0..31: q out (natural). blocks 32..95: content out -> scatter.
__global__ __launch_bounds__(256) void layer2_kernel(
    const float* __restrict__ q1,
    const float* __restrict__ qw2, const float* __restrict__ qb2, float* __restrict__ qv,
    const float* __restrict__ h1T, const float* __restrict__ W2,
    const float* __restrict__ b2, float* __restrict__ content,
    const int* __restrict__ chunk_rows, const int* __restrict__ chunk_plane,
    const int* __restrict__ nchunks_p)
{
    int bid = blockIdx.x;
    int tid = threadIdx.x;
    float4 c0 = {0.f,0.f,0.f,0.f}, c1 = {0.f,0.f,0.f,0.f};
    if (bid < 32) {
        int rt = bid >> 2, ct = bid & 3;
        int tr = tid >> 4, tc = tid & 15;
        int row = rt * 32 + tr * 2, col = ct * 64 + tc * 4;
        const float* a0 = q1 + (size_t)row * QH_;
        rgemm_inner(a0, a0 + QH_, qw2 + col, QO_, QH_, c0, c1);
        float4 bv = *reinterpret_cast<const float4*>(qb2 + col);
        c0.x += bv.x; c0.y += bv.y; c0.z += bv.z; c0.w += bv.w;
        c1.x += bv.x; c1.y += bv.y; c1.z += bv.z; c1.w += bv.w;
        *reinterpret_cast<float4*>(qv + (size_t)row * QO_ + col) = c0;
        *reinterpret_cast<float4*>(qv + (size_t)(row + 1) * QO_ + col) = c1;
    } else {
        int b2i = bid - 32;
        int c = b2i >> 2, jt = b2i & 3;
        if (c >= *nchunks_p) return;
        int p = chunk_plane[c];
        int tr = tid >> 3, tc = tid & 7;          // 32 x 8 threads
        int J = jt * 64 + tr * 2;
        int s0 = c * 32 + tc * 4;
        const float* a0 = W2 + ((size_t)p * DS_ + J) * DHID_;
        rgemm_inner(a0, a0 + DHID_, h1T + s0, SLOTS_, DHID_, c0, c1);
        float bj0 = b2[p * DS_ + J], bj1 = b2[p * DS_ + J + 1];
        int w0 = chunk_rows[s0], w1 = chunk_rows[s0 + 1];
        int w2w = chunk_rows[s0 + 2], w3 = chunk_rows[s0 + 3];
        if (w0 >= 0) { content[(size_t)w0 * DS_ + J] = c0.x + bj0; content[(size_t)w0 * DS_ + J + 1] = c1.x + bj1; }
        if (w1 >= 0) { content[(size_t)w1 * DS_ + J] = c0.y + bj0; content[(size_t)w1 * DS_ + J + 1] = c1.y + bj1; }
        if (w2w >= 0) { content[(size_t)w2w * DS_ + J] = c0.z + bj0; content[(size_t)w2w * DS_ + J + 1] = c1.z + bj1; }
        if (w3 >= 0) { content[(size_t)w3 * DS_ + J] = c0.w + bj0; content[(size_t)w3 * DS_ + J + 1] = c1.w + bj1; }
    }
}

__global__ __launch_bounds__(256) void score_kernel(
    const float* __restrict__ keys, const float* __restrict__ qv,
    const float* __restrict__ content, const int* __restrict__ neighbors,
    int* __restrict__ pos, float* __restrict__ s_out, float* __restrict__ ws_out,
    float* __restrict__ motor_out, float* __restrict__ co_out,
    float* __restrict__ vc_out, float* __restrict__ mp_all, int t)
{
    int w = blockIdx.x;
    int b = w >> 4;
    int tid = threadIdx.x;
    int pold = pos[w];
    __shared__ int nbr_s[32];
    __shared__ float part_s[8][32];
    __shared__ float sc_s[32];
    if (tid < 32) nbr_s[tid] = neighbors[(size_t)pold * K_ + tid];
    __syncthreads();
    int k = tid & 31, part = tid >> 5;
    int nk = nbr_s[k];
    const float* kp = keys + (size_t)nk * 256 + part * 32;
    const float* qp = qv + (size_t)w * 256 + part * 32;
    float acc = 0.f;
#pragma unroll
    for (int i = 0; i < 32; i += 4) {
        float4 kv = *reinterpret_cast<const float4*>(kp + i);
        float4 qq = *reinterpret_cast<const float4*>(qp + i);
        acc += kv.x * qq.x + kv.y * qq.y + kv.z * qq.z + kv.w * qq.w;
    }
    part_s[part][k] = acc;
    __syncthreads();
    if (tid < 32) {
        float s = 0.f;
#pragma unroll
        for (int p8 = 0; p8 < 8; ++p8) s += part_s[p8][tid];
        sc_s[tid] = s * SCORE_SCALE;
    }
    __syncthreads();
    if (tid < 32) {
        float sv = sc_s[tid];
        float m = sv;
        for (int off = 1; off < 32; off <<= 1) m = fmaxf(m, __shfl_xor(m, off));
        float e = expf(sv - m);
        float ssum = e;
        for (int off = 1; off < 32; off <<= 1) ssum += __shfl_xor(ssum, off);
        float prob = e / ssum;
        atomicAdd(&mp_all[t * 32 + tid], prob);
        float bs = sv; int bi = tid;
        for (int off = 1; off < 32; off <<= 1) {
            float os = __shfl_xor(bs, off);
            int   oi = __shfl_xor(bi, off);
            if (os > bs || (os == bs && oi < bi)) { bs = os; bi = oi; }
        }
        if (tid == 0) {
            int next = nbr_s[bi];
            pos[w] = next;
            atomicAdd(&co_out[(size_t)pold * N_ + next], 1.0f);
            atomicAdd(&vc_out[next], 1.0f);
        }
    }
    float c = content[(size_t)w * DS_ + tid];
    atomicAdd(&s_out[((size_t)b * N_ + pold) * DS_ + tid], c);
    float wn = ws_out[(size_t)w * DS_ + tid] + c;
    ws_out[(size_t)w * DS_ + tid] = wn;
    atomicAdd(&motor_out[((size_t)b * T_ + t) * DS_ + tid], wn * (1.0f / H_));
}

__global__ __launch_bounds__(256) void final_kernel(
    const int* __restrict__ pos, const float* __restrict__ mp_all,
    float* __restrict__ pos_out, float* __restrict__ lb_out)
{
    int tid = threadIdx.x;
    pos_out[tid] = (float)pos[tid];
    float v = mp_all[tid] * (1.0f / 256.f);
    v = v * v;
    for (int off = 32; off > 0; off >>= 1) v += __shfl_down(v, off);
    __shared__ float red[4];
    if ((tid & 63) == 0) red[tid >> 6] = v;
    __syncthreads();
    if (tid == 0) lb_out[0] = (float)K_ * (red[0] + red[1] + red[2] + red[3]);
}

// ---------------- launch ----------------

extern "C" void kernel_launch(void* const* d_in, const int* in_sizes, int n_in,
                              void* d_out, int out_size, void* d_ws, size_t ws_size,
                              hipStream_t stream)
{
    const float* s_in      = (const float*)d_in[0];
    const float* node_id   = (const float*)d_in[1];
    const float* wstate_in = (const float*)d_in[2];
    const float* token     = (const float*)d_in[3];
    const float* norm_w    = (const float*)d_in[4];
    const float* W1        = (const float*)d_in[5];
    const float* b1        = (const float*)d_in[6];
    const float* W2        = (const float*)d_in[7];
    const float* b2        = (const float*)d_in[8];
    const float* qw1       = (const float*)d_in[9];
    const float* qb1       = (const float*)d_in[10];
    const float* qw2       = (const float*)d_in[11];
    const float* qb2       = (const float*)d_in[12];
    const float* kw1       = (const float*)d_in[13];
    const float* kb1       = (const float*)d_in[14];
    const float* kw2       = (const float*)d_in[15];
    const float* kb2       = (const float*)d_in[16];
    const int* walker_pos  = (const int*)d_in[17];
    const int* plane_idx   = (const int*)d_in[18];
    const int* neighbors   = (const int*)d_in[19];

    float* out = (float*)d_out;
    float* out_motor = out;                               // B*T*DS   = 32768
    float* out_s     = out_motor + 32768;                 // B*N*DS   = 16777216
    float* out_pos   = out_s + (size_t)16777216;          // B*H      = 256
    float* out_ws    = out_pos + 256;                     // B*H*DS   = 65536
    float* out_co    = out_ws + 65536;                    // N*N      = 16777216
    float* out_vc    = out_co + (size_t)16777216;         // N        = 4096
    float* out_lb    = out_vc + 4096;                     // 1

    // workspace: keys persistent; kh (setup-only) unioned with per-step bufs
    float* ws = (float*)d_ws;
    float* keys = ws;                                     // 4096*256 = 1048576
    float* U    = keys + 1048576;                         // union region (2M floats)
    float* kh      = U;                                   // 4096*512 = 2097152 (setup only)
    float* steer   = U;                                   // 256*896  = 229376
    float* steerT  = steer + 229376;                      // 896*512  = 458752
    float* h1T     = steerT + 458752;                     // 1024*512 = 524288
    float* q1v     = h1T + 524288;                        // 256*512  = 131072
    float* qvv     = q1v + 131072;                        // 256*256  = 65536
    float* content = qvv + 65536;                         // 256*256  = 65536  (sum 1474560 < 2097152)
    float* mp_all  = U + 2097152;                         // 8*32 = 256
    int* pos         = (int*)(mp_all + 256);              // 256
    int* plane_order = pos + 256;                         // 8*256 = 2048
    int* chunk_plane = plane_order + 2048;                // 16
    int* chunk_rows  = chunk_plane + 16;                  // 16*32 = 512
    int* slot_of     = chunk_rows + 512;                  // 256
    int* nchunks_p   = slot_of + 256;                     // 1

    hipMemsetAsync(out_motor, 0, 32768 * sizeof(float), stream);
    hipMemsetAsync(out_co, 0, (size_t)(16777216 + 4096 + 1) * sizeof(float), stream);
    hipMemcpyAsync(out_s, s_in, (size_t)16777216 * sizeof(float),
                   hipMemcpyDeviceToDevice, stream);
    hipMemcpyAsync(out_ws, wstate_in, (size_t)65536 * sizeof(float),
                   hipMemcpyDeviceToDevice, stream);

    init_kernel<<<1, 256, 0, stream>>>(walker_pos, plane_idx, pos, mp_all,
                                       plane_order, chunk_plane, chunk_rows,
                                       slot_of, nchunks_p);
    // keys = mlp2(node_id) precomputed for all N nodes (two register GEMMs)
    rgemm_nat_kernel<<<128 * 8, 256, 0, stream>>>(node_id, DID_, kw1, QH_, kb1, kh, 8, 1);
    rgemm_nat_kernel<<<128 * 4, 256, 0, stream>>>(kh, QH_, kw2, QO_, kb2, keys, 4, 0);

    for (int t = 0; t < T_; ++t) {
        steer_kernel<<<256, 256, 0, stream>>>(out_s, node_id, out_ws, token,
                                              norm_w, pos, slot_of, steer, steerT, t);
        layer1_kernel<<<64 + 16 * 16, 256, 0, stream>>>(steer, steerT,
                                                        qw1, qb1, q1v,
                                                        W1, b1, h1T,
                                                        chunk_plane, nchunks_p);
        layer2_kernel<<<32 + 16 * 4, 256, 0, stream>>>(q1v, qw2, qb2, qvv,
                                                       h1T, W2, b2, content,
                                                       chunk_rows, chunk_plane, nchunks_p);
        score_kernel<<<256, 256, 0, stream>>>(keys, qvv, content, neighbors, pos,
                                              out_s, out_ws, out_motor, out_co,
                                              out_vc, mp_all, t);
    }
    final_kernel<<<1, 256, 0, stream>>>(pos, mp_all, out_pos, out_lb);
}

// Round 4
// 833.537 us; speedup vs baseline: 1.4737x; 1.4737x over previous
//
#include <hip/hip_runtime.h>
#include <math.h>

#define B_    16
#define H_    16
#define N_    4096
#define T_    8
#define DS_   256
#define DID_  128
#define L_    8
#define K_    32
#define DHID_ 1024
#define DSTEER_ 896
#define QH_   512
#define QO_   256
#define NW_   256   // B*H walkers
#define SLOTS_ 512  // chunk-slot space: 16 chunks x 32 slots
#define SCORE_SCALE 0.022097086912079608f  // 1/(8*sqrt(32))

__device__ __forceinline__ float gelu_exact(float x) {
    return 0.5f * x * (1.0f + erff(x * 0.70710678118654752f));
}

#define FMA4(c, b, a) { c.x = fmaf(b.x, (a), c.x); c.y = fmaf(b.y, (a), c.y); \
                        c.z = fmaf(b.z, (a), c.z); c.w = fmaf(b.w, (a), c.w); }

__device__ __forceinline__ void gelu4(float4& v) {
    v.x = gelu_exact(v.x); v.y = gelu_exact(v.y);
    v.z = gelu_exact(v.z); v.w = gelu_exact(v.w);
}

// acc[2 rows][4 cols] += A[2 rows][K] * B[K][4 cols]; A rows in registers
// (K-chunks of 8), B streamed as coalesced float4 (ldb-strided).
__device__ __forceinline__ void rgemm_inner(
    const float* __restrict__ a0, const float* __restrict__ a1,
    const float* __restrict__ bp, int ldb, int K,
    float4& c0, float4& c1)
{
    for (int k = 0; k < K; k += 8) {
        const float4 a0l = *reinterpret_cast<const float4*>(a0 + k);
        const float4 a0h = *reinterpret_cast<const float4*>(a0 + k + 4);
        const float4 a1l = *reinterpret_cast<const float4*>(a1 + k);
        const float4 a1h = *reinterpret_cast<const float4*>(a1 + k + 4);
        const float* b8 = bp + (size_t)k * ldb;
#define KSTEP(o, av0, av1) { float4 bv = *reinterpret_cast<const float4*>(b8 + (size_t)(o) * ldb); \
                             FMA4(c0, bv, av0); FMA4(c1, bv, av1); }
        KSTEP(0, a0l.x, a1l.x)
        KSTEP(1, a0l.y, a1l.y)
        KSTEP(2, a0l.z, a1l.z)
        KSTEP(3, a0l.w, a1l.w)
        KSTEP(4, a0h.x, a1h.x)
        KSTEP(5, a0h.y, a1h.y)
        KSTEP(6, a0h.z, a1h.z)
        KSTEP(7, a0h.w, a1h.w)
#undef KSTEP
    }
}

// out[row][j] = act(A[row][:] @ B[:, j] + bias[j]); 32 rows x 64 cols per block.
__global__ __launch_bounds__(256) void rgemm_nat_kernel(
    const float* __restrict__ A, int DIN,
    const float* __restrict__ B, int JOUT,
    const float* __restrict__ bias, float* __restrict__ out,
    int ncol, int act)
{
    int rt = blockIdx.x / ncol, ct = blockIdx.x % ncol;
    int tid = threadIdx.x;
    int tr = tid >> 4, tc = tid & 15;
    int row = rt * 32 + tr * 2;
    int col = ct * 64 + tc * 4;
    const float* a0 = A + (size_t)row * DIN;
    float4 c0 = {0.f,0.f,0.f,0.f}, c1 = {0.f,0.f,0.f,0.f};
    rgemm_inner(a0, a0 + DIN, B + col, JOUT, DIN, c0, c1);
    float4 bv = *reinterpret_cast<const float4*>(bias + col);
    c0.x += bv.x; c0.y += bv.y; c0.z += bv.z; c0.w += bv.w;
    c1.x += bv.x; c1.y += bv.y; c1.z += bv.z; c1.w += bv.w;
    if (act) { gelu4(c0); gelu4(c1); }
    *reinterpret_cast<float4*>(out + (size_t)row * JOUT + col) = c0;
    *reinterpret_cast<float4*>(out + (size_t)(row + 1) * JOUT + col) = c1;
}

// ---------------- setup kernels ----------------

__global__ __launch_bounds__(256) void init_kernel(
    const int* __restrict__ walker_pos, const int* __restrict__ plane_idx,
    int* pos, float* mp_all, int* plane_order,
    int* chunk_plane, int* chunk_rows, int* slot_of, int* nchunks_p)
{
    int tid = threadIdx.x;
    pos[tid] = walker_pos[tid];
    mp_all[tid] = 0.f;                       // 8*32 = 256
    __shared__ int cnt_s[8];
    __shared__ int cplane_s[16], cbase_s[16];
    __shared__ int nch_s;
    int wave = tid >> 6, lane = tid & 63;
    for (int pp = wave; pp < 8; pp += 4) {
        int base = 0;
        for (int c0 = 0; c0 < NW_; c0 += 64) {
            int w = c0 + lane;
            bool hit = (plane_idx[w] == pp);
            unsigned long long mask = __ballot(hit);
            if (hit) {
                int rank = __popcll(mask & ((1ull << lane) - 1ull));
                plane_order[pp * NW_ + base + rank] = w;
            }
            base += __popcll(mask);
        }
        if (lane == 0) cnt_s[pp] = base;
    }
    __syncthreads();
    if (tid == 0) {
        int nc = 0;
        for (int p = 0; p < 8; ++p)
            for (int s0 = 0; s0 < cnt_s[p]; s0 += 32) {
                cplane_s[nc] = p; cbase_s[nc] = s0; ++nc;
            }
        nch_s = nc;
        *nchunks_p = nc;
    }
    __syncthreads();
    int nc = nch_s;
    for (int idx = tid; idx < 16 * 32; idx += 256) {
        int c = idx >> 5, i = idx & 31;
        int v = -1;
        if (c < nc) {
            int p = cplane_s[c];
            int r = cbase_s[c] + i;
            if (r < cnt_s[p]) v = plane_order[p * NW_ + r];
        }
        chunk_rows[c * 32 + i] = v;
        if (v >= 0) slot_of[v] = c * 32 + i;
        if (i == 0) chunk_plane[c] = (c < nc) ? cplane_s[c] : 0;
    }
}

// ---------------- per-step kernels ----------------

__global__ __launch_bounds__(256) void steer_kernel(
    const float* __restrict__ s_out, const float* __restrict__ node_id,
    const float* __restrict__ ws_out, const float* __restrict__ token_embed,
    const float* __restrict__ norm_w, const int* __restrict__ pos,
    const int* __restrict__ slot_of,
    float* __restrict__ steer, float* __restrict__ steerT, int t)
{
    int w = blockIdx.x;
    int b = w >> 4;
    int tid = threadIdx.x;
    int p = pos[w];
    int slot = slot_of[w];
    float sc = s_out[((size_t)b * N_ + p) * DS_ + tid];
    float v = sc * sc;
    for (int off = 32; off > 0; off >>= 1) v += __shfl_down(v, off);
    __shared__ float red[4];
    if ((tid & 63) == 0) red[tid >> 6] = v;
    __syncthreads();
    float tot = red[0] + red[1] + red[2] + red[3];
    float r = rsqrtf(tot * (1.0f / DS_) + 1e-6f);
    float* st = steer + (size_t)w * DSTEER_;
    float v0 = sc * r * norm_w[tid];
    float v2 = ws_out[(size_t)w * DS_ + tid];
    float v3 = token_embed[((size_t)b * T_ + t) * DS_ + tid];
    st[tid] = v0;
    st[384 + tid] = v2;
    st[640 + tid] = v3;
    steerT[(size_t)tid * SLOTS_ + slot] = v0;
    steerT[(size_t)(384 + tid) * SLOTS_ + slot] = v2;
    steerT[(size_t)(640 + tid) * SLOTS_ + slot] = v3;
    if (tid < 128) {
        float v1 = node_id[(size_t)p * DID_ + tid];
        st[256 + tid] = v1;
        steerT[(size_t)(256 + tid) * SLOTS_ + slot] = v1;
    }
}

// K-split x4. blocks 0..255: q hidden partials; 256..1279: content hidden partials.
__global__ __launch_bounds__(256) void layer1_kernel(
    const float* __restrict__ steer, const float* __restrict__ steerT,
    const float* __restrict__ qw1, float* __restrict__ q1p,
    const float* __restrict__ W1, float* __restrict__ h1p,
    const int* __restrict__ chunk_plane, const int* __restrict__ nchunks_p)
{
    int bid = blockIdx.x;
    int tid = threadIdx.x;
    float4 c0 = {0.f,0.f,0.f,0.f}, c1 = {0.f,0.f,0.f,0.f};
    if (bid < 256) {                            // q hidden, K = 4 x 224
        int kp = bid & 3, tile = bid >> 2;
        int rt = tile >> 3, ct = tile & 7;
        int tr = tid >> 4, tc = tid & 15;
        int row = rt * 32 + tr * 2, col = ct * 64 + tc * 4;
        const float* a0 = steer + (size_t)row * DSTEER_ + kp * 224;
        rgemm_inner(a0, a0 + DSTEER_, qw1 + (size_t)(kp * 224) * QH_ + col, QH_, 224, c0, c1);
        float* o = q1p + (size_t)kp * 131072;
        *reinterpret_cast<float4*>(o + (size_t)row * QH_ + col) = c0;
        *reinterpret_cast<float4*>(o + (size_t)(row + 1) * QH_ + col) = c1;
    } else {                                    // content hidden, K = 4 x 224
        int b2 = bid - 256;
        int kp = b2 & 3, tile = b2 >> 2;
        int c = tile >> 4, jt = tile & 15;
        if (c >= *nchunks_p) return;
        int p = chunk_plane[c];
        int tr = tid >> 3, tc = tid & 7;          // 32 x 8 threads
        int J = jt * 64 + tr * 2;
        int slot = c * 32 + tc * 4;
        const float* a0 = W1 + ((size_t)p * DHID_ + J) * DSTEER_ + kp * 224;
        rgemm_inner(a0, a0 + DSTEER_, steerT + (size_t)(kp * 224) * SLOTS_ + slot, SLOTS_, 224, c0, c1);
        float* o = h1p + (size_t)kp * 524288;
        *reinterpret_cast<float4*>(o + (size_t)J * SLOTS_ + slot) = c0;
        *reinterpret_cast<float4*>(o + (size_t)(J + 1) * SLOTS_ + slot) = c1;
    }
}

// combine partials: h1T = gelu(sum h1p + b1), q1 = gelu(sum q1p + qb1).
// h1T aliases h1p[0]; q1 aliases q1p[0] (elementwise read-then-write, safe).
__global__ __launch_bounds__(256) void combine1_kernel(
    float* __restrict__ h1p, float* __restrict__ q1p,
    const float* __restrict__ b1, const float* __restrict__ qb1,
    const int* __restrict__ chunk_plane)
{
    int idx = blockIdx.x * 256 + threadIdx.x;      // 163840 total
    if (idx < 131072) {                            // content: [1024 J][512 slots]
        int J = idx >> 7, s4 = (idx & 127) << 2;
        size_t off = (size_t)J * SLOTS_ + s4;
        float4 v0 = *reinterpret_cast<const float4*>(h1p + off);
        float4 v1 = *reinterpret_cast<const float4*>(h1p + 524288 + off);
        float4 v2 = *reinterpret_cast<const float4*>(h1p + 1048576 + off);
        float4 v3 = *reinterpret_cast<const float4*>(h1p + 1572864 + off);
        float bj = b1[chunk_plane[s4 >> 5] * DHID_ + J];
        float4 r;
        r.x = gelu_exact(v0.x + v1.x + v2.x + v3.x + bj);
        r.y = gelu_exact(v0.y + v1.y + v2.y + v3.y + bj);
        r.z = gelu_exact(v0.z + v1.z + v2.z + v3.z + bj);
        r.w = gelu_exact(v0.w + v1.w + v2.w + v3.w + bj);
        *reinterpret_cast<float4*>(h1p + off) = r;
    } else {                                       // q: [256 rows][512 cols]
        int i2 = idx - 131072;
        int row = i2 >> 7, c4 = (i2 & 127) << 2;
        size_t off = (size_t)row * QH_ + c4;
        float4 v0 = *reinterpret_cast<const float4*>(q1p + off);
        float4 v1 = *reinterpret_cast<const float4*>(q1p + 131072 + off);
        float4 v2 = *reinterpret_cast<const float4*>(q1p + 262144 + off);
        float4 v3 = *reinterpret_cast<const float4*>(q1p + 393216 + off);
        float4 bv = *reinterpret_cast<const float4*>(qb1 + c4);
        float4 r;
        r.x = gelu_exact(v0.x + v1.x + v2.x + v3.x + bv.x);
        r.y = gelu_exact(v0.y + v1.y + v2.y + v3.y + bv.y);
        r.z = gelu_exact(v0.z + v1.z + v2.z + v3.z + bv.z);
        r.w = gelu_exact(v0.w + v1.w + v2.w + v3.w + bv.w);
        *reinterpret_cast<float4*>(q1p + off) = r;
    }
}

// K-split x4. blocks 0..127: q out partials; 128..383: content out partials.
__global__ __launch_bounds__(256) void layer2_kernel(
    const float* __restrict__ q1, const float* __restrict__ qw2, float* __restrict__ q2p,
    const float* __restrict__ h1T, const float* __restrict__ W2, float* __restrict__ c2p,
    const int* __restrict__ chunk_plane, const int* __restrict__ nchunks_p)
{
    int bid = blockIdx.x;
    int tid = threadIdx.x;
    float4 c0 = {0.f,0.f,0.f,0.f}, c1 = {0.f,0.f,0.f,0.f};
    if (bid < 128) {                            // q out, K = 4 x 128
        int kp = bid & 3, tile = bid >> 2;
        int rt = tile >> 2, ct = tile & 3;
        int tr = tid >> 4, tc = tid & 15;
        int row = rt * 32 + tr * 2, col = ct * 64 + tc * 4;
        const float* a0 = q1 + (size_t)row * QH_ + kp * 128;
        rgemm_inner(a0, a0 + QH_, qw2 + (size_t)(kp * 128) * QO_ + col, QO_, 128, c0, c1);
        float* o = q2p + (size_t)kp * 65536;
        *reinterpret_cast<float4*>(o + (size_t)row * QO_ + col) = c0;
        *reinterpret_cast<float4*>(o + (size_t)(row + 1) * QO_ + col) = c1;
    } else {                                    // content out, K = 4 x 256
        int b2i = bid - 128;
        int kp = b2i & 3, tile = b2i >> 2;
        int c = tile >> 2, jt = tile & 3;
        if (c >= *nchunks_p) return;
        int p = chunk_plane[c];
        int tr = tid >> 3, tc = tid & 7;          // 32 x 8 threads
        int J = jt * 64 + tr * 2;
        int slot = c * 32 + tc * 4;
        const float* a0 = W2 + ((size_t)p * DS_ + J) * DHID_ + kp * 256;
        rgemm_inner(a0, a0 + DHID_, h1T + (size_t)(kp * 256) * SLOTS_ + slot, SLOTS_, 256, c0, c1);
        float* o = c2p + (size_t)kp * 131072;
        *reinterpret_cast<float4*>(o + (size_t)J * SLOTS_ + slot) = c0;
        *reinterpret_cast<float4*>(o + (size_t)(J + 1) * SLOTS_ + slot) = c1;
    }
}

// combine partials: content[w][J] = sum c2p + b2 (scatter), qv = sum q2p + qb2.
__global__ __launch_bounds__(256) void combine2_kernel(
    const float* __restrict__ c2p, const float* __restrict__ q2p,
    const float* __restrict__ b2, const float* __restrict__ qb2,
    const int* __restrict__ chunk_rows, const int* __restrict__ chunk_plane,
    float* __restrict__ content, float* __restrict__ qv)
{
    int idx = blockIdx.x * 256 + threadIdx.x;      // 49152 total
    if (idx < 32768) {                             // content: [256 J][512 slots]
        int J = idx >> 7, s4 = (idx & 127) << 2;
        size_t off = (size_t)J * SLOTS_ + s4;
        float4 v0 = *reinterpret_cast<const float4*>(c2p + off);
        float4 v1 = *reinterpret_cast<const float4*>(c2p + 131072 + off);
        float4 v2 = *reinterpret_cast<const float4*>(c2p + 262144 + off);
        float4 v3 = *reinterpret_cast<const float4*>(c2p + 393216 + off);
        float bj = b2[chunk_plane[s4 >> 5] * DS_ + J];
        float r0 = v0.x + v1.x + v2.x + v3.x + bj;
        float r1 = v0.y + v1.y + v2.y + v3.y + bj;
        float r2 = v0.z + v1.z + v2.z + v3.z + bj;
        float r3 = v0.w + v1.w + v2.w + v3.w + bj;
        int w0 = chunk_rows[s4], w1 = chunk_rows[s4 + 1];
        int w2 = chunk_rows[s4 + 2], w3 = chunk_rows[s4 + 3];
        if (w0 >= 0) content[(size_t)w0 * DS_ + J] = r0;
        if (w1 >= 0) content[(size_t)w1 * DS_ + J] = r1;
        if (w2 >= 0) content[(size_t)w2 * DS_ + J] = r2;
        if (w3 >= 0) content[(size_t)w3 * DS_ + J] = r3;
    } else {                                       // q: [256 rows][256 cols]
        int i2 = idx - 32768;
        int row = i2 >> 6, c4 = (i2 & 63) << 2;
        size_t off = (size_t)row * QO_ + c4;
        float4 v0 = *reinterpret_cast<const float4*>(q2p + off);
        float4 v1 = *reinterpret_cast<const float4*>(q2p + 65536 + off);
        float4 v2 = *reinterpret_cast<const float4*>(q2p + 131072 + off);
        float4 v3 = *reinterpret_cast<const float4*>(q2p + 196608 + off);
        float4 bv = *reinterpret_cast<const float4*>(qb2 + c4);
        float4 r;
        r.x = v0.x + v1.x + v2.x + v3.x + bv.x;
        r.y = v0.y + v1.y + v2.y + v3.y + bv.y;
        r.z = v0.z + v1.z + v2.z + v3.z + bv.z;
        r.w = v0.w + v1.w + v2.w + v3.w + bv.w;
        *reinterpret_cast<float4*>(qv + off) = r;
    }
}

__global__ __launch_bounds__(256) void score_kernel(
    const float* __restrict__ keys, const float* __restrict__ qv,
    const float* __restrict__ content, const int* __restrict__ neighbors,
    int* __restrict__ pos, float* __restrict__ s_out, float* __restrict__ ws_out,
    float* __restrict__ motor_out, float* __restrict__ co_out,
    float* __restrict__ vc_out, float* __restrict__ mp_all, int t)
{
    int w = blockIdx.x;
    int b = w >> 4;
    int tid = threadIdx.x;
    int pold = pos[w];
    __shared__ int nbr_s[32];
    __shared__ float part_s[8][32];
    __shared__ float sc_s[32];
    if (tid < 32) nbr_s[tid] = neighbors[(size_t)pold * K_ + tid];
    __syncthreads();
    int k = tid & 31, part = tid >> 5;
    int nk = nbr_s[k];
    const float* kp = keys + (size_t)nk * 256 + part * 32;
    const float* qp = qv + (size_t)w * 256 + part * 32;
    float acc = 0.f;
#pragma unroll
    for (int i = 0; i < 32; i += 4) {
        float4 kv = *reinterpret_cast<const float4*>(kp + i);
        float4 qq = *reinterpret_cast<const float4*>(qp + i);
        acc += kv.x * qq.x + kv.y * qq.y + kv.z * qq.z + kv.w * qq.w;
    }
    part_s[part][k] = acc;
    __syncthreads();
    if (tid < 32) {
        float s = 0.f;
#pragma unroll
        for (int p8 = 0; p8 < 8; ++p8) s += part_s[p8][tid];
        sc_s[tid] = s * SCORE_SCALE;
    }
    __syncthreads();
    if (tid < 32) {
        float sv = sc_s[tid];
        float m = sv;
        for (int off = 1; off < 32; off <<= 1) m = fmaxf(m, __shfl_xor(m, off));
        float e = expf(sv - m);
        float ssum = e;
        for (int off = 1; off < 32; off <<= 1) ssum += __shfl_xor(ssum, off);
        float prob = e / ssum;
        atomicAdd(&mp_all[t * 32 + tid], prob);
        float bs = sv; int bi = tid;
        for (int off = 1; off < 32; off <<= 1) {
            float os = __shfl_xor(bs, off);
            int   oi = __shfl_xor(bi, off);
            if (os > bs || (os == bs && oi < bi)) { bs = os; bi = oi; }
        }
        if (tid == 0) {
            int next = nbr_s[bi];
            pos[w] = next;
            atomicAdd(&co_out[(size_t)pold * N_ + next], 1.0f);
            atomicAdd(&vc_out[next], 1.0f);
        }
    }
    float c = content[(size_t)w * DS_ + tid];
    atomicAdd(&s_out[((size_t)b * N_ + pold) * DS_ + tid], c);
    float wn = ws_out[(size_t)w * DS_ + tid] + c;
    ws_out[(size_t)w * DS_ + tid] = wn;
    atomicAdd(&motor_out[((size_t)b * T_ + t) * DS_ + tid], wn * (1.0f / H_));
}

__global__ __launch_bounds__(256) void final_kernel(
    const int* __restrict__ pos, const float* __restrict__ mp_all,
    float* __restrict__ pos_out, float* __restrict__ lb_out)
{
    int tid = threadIdx.x;
    pos_out[tid] = (float)pos[tid];
    float v = mp_all[tid] * (1.0f / 256.f);
    v = v * v;
    for (int off = 32; off > 0; off >>= 1) v += __shfl_down(v, off);
    __shared__ float red[4];
    if ((tid & 63) == 0) red[tid >> 6] = v;
    __syncthreads();
    if (tid == 0) lb_out[0] = (float)K_ * (red[0] + red[1] + red[2] + red[3]);
}

// ---------------- launch ----------------

extern "C" void kernel_launch(void* const* d_in, const int* in_sizes, int n_in,
                              void* d_out, int out_size, void* d_ws, size_t ws_size,
                              hipStream_t stream)
{
    const float* s_in      = (const float*)d_in[0];
    const float* node_id   = (const float*)d_in[1];
    const float* wstate_in = (const float*)d_in[2];
    const float* token     = (const float*)d_in[3];
    const float* norm_w    = (const float*)d_in[4];
    const float* W1        = (const float*)d_in[5];
    const float* b1        = (const float*)d_in[6];
    const float* W2        = (const float*)d_in[7];
    const float* b2        = (const float*)d_in[8];
    const float* qw1       = (const float*)d_in[9];
    const float* qb1       = (const float*)d_in[10];
    const float* qw2       = (const float*)d_in[11];
    const float* qb2       = (const float*)d_in[12];
    const float* kw1       = (const float*)d_in[13];
    const float* kb1       = (const float*)d_in[14];
    const float* kw2       = (const float*)d_in[15];
    const float* kb2       = (const float*)d_in[16];
    const int* walker_pos  = (const int*)d_in[17];
    const int* plane_idx   = (const int*)d_in[18];
    const int* neighbors   = (const int*)d_in[19];

    float* out = (float*)d_out;
    float* out_motor = out;                               // B*T*DS   = 32768
    float* out_s     = out_motor + 32768;                 // B*N*DS   = 16777216
    float* out_pos   = out_s + (size_t)16777216;          // B*H      = 256
    float* out_ws    = out_pos + 256;                     // B*H*DS   = 65536
    float* out_co    = out_ws + 65536;                    // N*N      = 16777216
    float* out_vc    = out_co + (size_t)16777216;         // N        = 4096
    float* out_lb    = out_vc + 4096;                     // 1

    // workspace layout (floats). PART region is time-shared:
    //   setup:  kh (4096x512 = 2097152)
    //   layer1: h1p[4][1024][512] (2097152) | q1p[4][256][512] (524288) at +2097152
    //   after combine1: h1T = h1p[0] (524288), q1 = q1p[0]
    //   layer2: c2p[4][256][512] at PART+524288; q2p[4][256][256] at PART+1048576
    float* ws = (float*)d_ws;
    float* keys    = ws;                                  // 1048576
    float* steer   = keys + 1048576;                      // 229376
    float* steerT  = steer + 229376;                      // 896*512 = 458752
    float* qvv     = steerT + 458752;                     // 65536
    float* content = qvv + 65536;                         // 65536
    float* PART    = content + 65536;                     // 2621440
    float* kh   = PART;
    float* h1p  = PART;
    float* q1p  = PART + 2097152;
    float* h1T  = PART;                                   // alias h1p[0]
    float* q1v  = PART + 2097152;                         // alias q1p[0]
    float* c2p  = PART + 524288;
    float* q2p  = PART + 1048576;
    float* mp_all = PART + 2621440;                       // 256
    int* pos         = (int*)(mp_all + 256);              // 256
    int* plane_order = pos + 256;                         // 2048
    int* chunk_plane = plane_order + 2048;                // 16
    int* chunk_rows  = chunk_plane + 16;                  // 512
    int* slot_of     = chunk_rows + 512;                  // 256
    int* nchunks_p   = slot_of + 256;                     // 1
    // total ~4.49M floats ~= 18 MB

    hipMemsetAsync(out_motor, 0, 32768 * sizeof(float), stream);
    hipMemsetAsync(out_co, 0, (size_t)(16777216 + 4096 + 1) * sizeof(float), stream);
    hipMemcpyAsync(out_s, s_in, (size_t)16777216 * sizeof(float),
                   hipMemcpyDeviceToDevice, stream);
    hipMemcpyAsync(out_ws, wstate_in, (size_t)65536 * sizeof(float),
                   hipMemcpyDeviceToDevice, stream);

    init_kernel<<<1, 256, 0, stream>>>(walker_pos, plane_idx, pos, mp_all,
                                       plane_order, chunk_plane, chunk_rows,
                                       slot_of, nchunks_p);
    // keys = mlp2(node_id) precomputed for all N nodes (two register GEMMs)
    rgemm_nat_kernel<<<128 * 8, 256, 0, stream>>>(node_id, DID_, kw1, QH_, kb1, kh, 8, 1);
    rgemm_nat_kernel<<<128 * 4, 256, 0, stream>>>(kh, QH_, kw2, QO_, kb2, keys, 4, 0);

    for (int t = 0; t < T_; ++t) {
        steer_kernel<<<256, 256, 0, stream>>>(out_s, node_id, out_ws, token,
                                              norm_w, pos, slot_of, steer, steerT, t);
        layer1_kernel<<<1280, 256, 0, stream>>>(steer, steerT, qw1, q1p,
                                                W1, h1p, chunk_plane, nchunks_p);
        combine1_kernel<<<640, 256, 0, stream>>>(h1p, q1p, b1, qb1, chunk_plane);
        layer2_kernel<<<384, 256, 0, stream>>>(q1v, qw2, q2p, h1T, W2, c2p,
                                               chunk_plane, nchunks_p);
        combine2_kernel<<<192, 256, 0, stream>>>(c2p, q2p, b2, qb2,
                                                 chunk_rows, chunk_plane,
                                                 content, qvv);
        score_kernel<<<256, 256, 0, stream>>>(keys, qvv, content, neighbors, pos,
                                              out_s, out_ws, out_motor, out_co,
                                              out_vc, mp_all, t);
    }
    final_kernel<<<1, 256, 0, stream>>>(pos, mp_all, out_pos, out_lb);
}

// Round 5
// 800.622 us; speedup vs baseline: 1.5342x; 1.0411x over previous
//
#include <hip/hip_runtime.h>
#include <math.h>

#define B_    16
#define H_    16
#define N_    4096
#define T_    8
#define DS_   256
#define DID_  128
#define L_    8
#define K_    32
#define DHID_ 1024
#define DSTEER_ 896
#define QH_   512
#define QO_   256
#define NW_   256   // B*H walkers
#define SLOTS_ 512  // chunk-slot space: 16 chunks x 32 slots
#define SCORE_SCALE 0.022097086912079608f  // 1/(8*sqrt(32))

__device__ __forceinline__ float gelu_exact(float x) {
    return 0.5f * x * (1.0f + erff(x * 0.70710678118654752f));
}

#define FMA4(c, b, a) { c.x = fmaf(b.x, (a), c.x); c.y = fmaf(b.y, (a), c.y); \
                        c.z = fmaf(b.z, (a), c.z); c.w = fmaf(b.w, (a), c.w); }

__device__ __forceinline__ void gelu4(float4& v) {
    v.x = gelu_exact(v.x); v.y = gelu_exact(v.y);
    v.z = gelu_exact(v.z); v.w = gelu_exact(v.w);
}

// acc[2 rows][4 cols] += A[2 rows][K] * B[K][4 cols]; A rows in registers
// (K-chunks of 8), B streamed as coalesced float4 (ldb-strided).
__device__ __forceinline__ void rgemm_inner(
    const float* __restrict__ a0, const float* __restrict__ a1,
    const float* __restrict__ bp, int ldb, int K,
    float4& c0, float4& c1)
{
    for (int k = 0; k < K; k += 8) {
        const float4 a0l = *reinterpret_cast<const float4*>(a0 + k);
        const float4 a0h = *reinterpret_cast<const float4*>(a0 + k + 4);
        const float4 a1l = *reinterpret_cast<const float4*>(a1 + k);
        const float4 a1h = *reinterpret_cast<const float4*>(a1 + k + 4);
        const float* b8 = bp + (size_t)k * ldb;
#define KSTEP(o, av0, av1) { float4 bv = *reinterpret_cast<const float4*>(b8 + (size_t)(o) * ldb); \
                             FMA4(c0, bv, av0); FMA4(c1, bv, av1); }
        KSTEP(0, a0l.x, a1l.x)
        KSTEP(1, a0l.y, a1l.y)
        KSTEP(2, a0l.z, a1l.z)
        KSTEP(3, a0l.w, a1l.w)
        KSTEP(4, a0h.x, a1h.x)
        KSTEP(5, a0h.y, a1h.y)
        KSTEP(6, a0h.z, a1h.z)
        KSTEP(7, a0h.w, a1h.w)
#undef KSTEP
    }
}

// out[row][j] = act(A[row][:] @ B[:, j] + bias[j]); 32 rows x 64 cols per block.
__global__ __launch_bounds__(256) void rgemm_nat_kernel(
    const float* __restrict__ A, int DIN,
    const float* __restrict__ B, int JOUT,
    const float* __restrict__ bias, float* __restrict__ out,
    int ncol, int act)
{
    int rt = blockIdx.x / ncol, ct = blockIdx.x % ncol;
    int tid = threadIdx.x;
    int tr = tid >> 4, tc = tid & 15;
    int row = rt * 32 + tr * 2;
    int col = ct * 64 + tc * 4;
    const float* a0 = A + (size_t)row * DIN;
    float4 c0 = {0.f,0.f,0.f,0.f}, c1 = {0.f,0.f,0.f,0.f};
    rgemm_inner(a0, a0 + DIN, B + col, JOUT, DIN, c0, c1);
    float4 bv = *reinterpret_cast<const float4*>(bias + col);
    c0.x += bv.x; c0.y += bv.y; c0.z += bv.z; c0.w += bv.w;
    c1.x += bv.x; c1.y += bv.y; c1.z += bv.z; c1.w += bv.w;
    if (act) { gelu4(c0); gelu4(c1); }
    *reinterpret_cast<float4*>(out + (size_t)row * JOUT + col) = c0;
    *reinterpret_cast<float4*>(out + (size_t)(row + 1) * JOUT + col) = c1;
}

// ---------------- init: zero outputs + restore state (replaces slow fills) ----
__global__ __launch_bounds__(256) void biginit_kernel(
    const float* __restrict__ s_in, const float* __restrict__ ws_in,
    float* __restrict__ out_motor, float* __restrict__ out_s,
    float* __restrict__ out_ws, float* __restrict__ out_co,
    float* __restrict__ out_vc, float* __restrict__ out_lb)
{
    const float4 z = {0.f, 0.f, 0.f, 0.f};
    int gid = blockIdx.x * 256 + threadIdx.x;
    int stride = gridDim.x * 256;
    float4* co4 = reinterpret_cast<float4*>(out_co);
    float4* s4o = reinterpret_cast<float4*>(out_s);
    const float4* s4i = reinterpret_cast<const float4*>(s_in);
    for (int i = gid; i < 4194304; i += stride) co4[i] = z;
    for (int i = gid; i < 4194304; i += stride) s4o[i] = s4i[i];
    float4* m4 = reinterpret_cast<float4*>(out_motor);
    for (int i = gid; i < 8192; i += stride) m4[i] = z;
    float4* w4o = reinterpret_cast<float4*>(out_ws);
    const float4* w4i = reinterpret_cast<const float4*>(ws_in);
    for (int i = gid; i < 16384; i += stride) w4o[i] = w4i[i];
    float4* v4 = reinterpret_cast<float4*>(out_vc);
    for (int i = gid; i < 1024; i += stride) v4[i] = z;
    if (gid == 0) out_lb[0] = 0.f;
}

// ---------------- setup kernels ----------------

__global__ __launch_bounds__(256) void init_kernel(
    const int* __restrict__ walker_pos, const int* __restrict__ plane_idx,
    int* pos, float* mp_all, int* plane_order,
    int* chunk_plane, int* chunk_rows, int* slot_of, int* nchunks_p)
{
    int tid = threadIdx.x;
    pos[tid] = walker_pos[tid];
    mp_all[tid] = 0.f;                       // 8*32 = 256
    __shared__ int cnt_s[8];
    __shared__ int cplane_s[16], cbase_s[16];
    __shared__ int nch_s;
    int wave = tid >> 6, lane = tid & 63;
    for (int pp = wave; pp < 8; pp += 4) {
        int base = 0;
        for (int c0 = 0; c0 < NW_; c0 += 64) {
            int w = c0 + lane;
            bool hit = (plane_idx[w] == pp);
            unsigned long long mask = __ballot(hit);
            if (hit) {
                int rank = __popcll(mask & ((1ull << lane) - 1ull));
                plane_order[pp * NW_ + base + rank] = w;
            }
            base += __popcll(mask);
        }
        if (lane == 0) cnt_s[pp] = base;
    }
    __syncthreads();
    if (tid == 0) {
        int nc = 0;
        for (int p = 0; p < 8; ++p)
            for (int s0 = 0; s0 < cnt_s[p]; s0 += 32) {
                cplane_s[nc] = p; cbase_s[nc] = s0; ++nc;
            }
        nch_s = nc;
        *nchunks_p = nc;
    }
    __syncthreads();
    int nc = nch_s;
    for (int idx = tid; idx < 16 * 32; idx += 256) {
        int c = idx >> 5, i = idx & 31;
        int v = -1;
        if (c < nc) {
            int p = cplane_s[c];
            int r = cbase_s[c] + i;
            if (r < cnt_s[p]) v = plane_order[p * NW_ + r];
        }
        chunk_rows[c * 32 + i] = v;
        if (v >= 0) slot_of[v] = c * 32 + i;
        if (i == 0) chunk_plane[c] = (c < nc) ? cplane_s[c] : 0;
    }
}

// ---------------- per-step kernels ----------------

__global__ __launch_bounds__(256) void steer_kernel(
    const float* __restrict__ s_out, const float* __restrict__ node_id,
    const float* __restrict__ ws_out, const float* __restrict__ token_embed,
    const float* __restrict__ norm_w, const int* __restrict__ pos,
    const int* __restrict__ slot_of,
    float* __restrict__ steer, float* __restrict__ steerT, int t)
{
    int w = blockIdx.x;
    int b = w >> 4;
    int tid = threadIdx.x;
    int p = pos[w];
    int slot = slot_of[w];
    float sc = s_out[((size_t)b * N_ + p) * DS_ + tid];
    float v = sc * sc;
    for (int off = 32; off > 0; off >>= 1) v += __shfl_down(v, off);
    __shared__ float red[4];
    if ((tid & 63) == 0) red[tid >> 6] = v;
    __syncthreads();
    float tot = red[0] + red[1] + red[2] + red[3];
    float r = rsqrtf(tot * (1.0f / DS_) + 1e-6f);
    float* st = steer + (size_t)w * DSTEER_;
    float v0 = sc * r * norm_w[tid];
    float v2 = ws_out[(size_t)w * DS_ + tid];
    float v3 = token_embed[((size_t)b * T_ + t) * DS_ + tid];
    st[tid] = v0;
    st[384 + tid] = v2;
    st[640 + tid] = v3;
    steerT[(size_t)tid * SLOTS_ + slot] = v0;
    steerT[(size_t)(384 + tid) * SLOTS_ + slot] = v2;
    steerT[(size_t)(640 + tid) * SLOTS_ + slot] = v3;
    if (tid < 128) {
        float v1 = node_id[(size_t)p * DID_ + tid];
        st[256 + tid] = v1;
        steerT[(size_t)(256 + tid) * SLOTS_ + slot] = v1;
    }
}

// K-split x8. blocks 0..511: q hidden partials (K=112); 512..2559: content (K=112).
__global__ __launch_bounds__(256) void layer1_kernel(
    const float* __restrict__ steer, const float* __restrict__ steerT,
    const float* __restrict__ qw1, float* __restrict__ q1p,
    const float* __restrict__ W1, float* __restrict__ h1p,
    const int* __restrict__ chunk_plane, const int* __restrict__ nchunks_p)
{
    int bid = blockIdx.x;
    int tid = threadIdx.x;
    float4 c0 = {0.f,0.f,0.f,0.f}, c1 = {0.f,0.f,0.f,0.f};
    if (bid < 512) {                            // q hidden
        int kp = bid & 7, tile = bid >> 3;      // 64 tiles
        int rt = tile >> 3, ct = tile & 7;
        int tr = tid >> 4, tc = tid & 15;
        int row = rt * 32 + tr * 2, col = ct * 64 + tc * 4;
        const float* a0 = steer + (size_t)row * DSTEER_ + kp * 112;
        rgemm_inner(a0, a0 + DSTEER_, qw1 + (size_t)(kp * 112) * QH_ + col, QH_, 112, c0, c1);
        float* o = q1p + (size_t)kp * 131072;
        *reinterpret_cast<float4*>(o + (size_t)row * QH_ + col) = c0;
        *reinterpret_cast<float4*>(o + (size_t)(row + 1) * QH_ + col) = c1;
    } else {                                    // content hidden
        int b2 = bid - 512;
        int kp = b2 & 7, tile = b2 >> 3;        // 256 tiles
        int c = tile >> 4, jt = tile & 15;
        if (c >= *nchunks_p) return;
        int p = chunk_plane[c];
        int tr = tid >> 3, tc = tid & 7;        // 32 x 8 threads
        int J = jt * 64 + tr * 2;
        int slot = c * 32 + tc * 4;
        const float* a0 = W1 + ((size_t)p * DHID_ + J) * DSTEER_ + kp * 112;
        rgemm_inner(a0, a0 + DSTEER_, steerT + (size_t)(kp * 112) * SLOTS_ + slot, SLOTS_, 112, c0, c1);
        float* o = h1p + (size_t)kp * 524288;
        *reinterpret_cast<float4*>(o + (size_t)J * SLOTS_ + slot) = c0;
        *reinterpret_cast<float4*>(o + (size_t)(J + 1) * SLOTS_ + slot) = c1;
    }
}

// combine partials: h1T = gelu(sum h1p + b1) into h1p[0]; q1 likewise into q1p[0].
__global__ __launch_bounds__(256) void combine1_kernel(
    float* __restrict__ h1p, float* __restrict__ q1p,
    const float* __restrict__ b1, const float* __restrict__ qb1,
    const int* __restrict__ chunk_plane)
{
    int idx = blockIdx.x * 256 + threadIdx.x;      // 163840 total
    if (idx < 131072) {                            // content: [1024 J][512 slots]
        int J = idx >> 7, s4 = (idx & 127) << 2;
        size_t off = (size_t)J * SLOTS_ + s4;
        float4 a = {0.f,0.f,0.f,0.f};
#pragma unroll
        for (int kp = 0; kp < 8; ++kp) {
            float4 v = *reinterpret_cast<const float4*>(h1p + (size_t)kp * 524288 + off);
            a.x += v.x; a.y += v.y; a.z += v.z; a.w += v.w;
        }
        float bj = b1[chunk_plane[s4 >> 5] * DHID_ + J];
        float4 r;
        r.x = gelu_exact(a.x + bj);
        r.y = gelu_exact(a.y + bj);
        r.z = gelu_exact(a.z + bj);
        r.w = gelu_exact(a.w + bj);
        *reinterpret_cast<float4*>(h1p + off) = r;
    } else {                                       // q: [256 rows][512 cols]
        int i2 = idx - 131072;
        int row = i2 >> 7, c4 = (i2 & 127) << 2;
        size_t off = (size_t)row * QH_ + c4;
        float4 a = {0.f,0.f,0.f,0.f};
#pragma unroll
        for (int kp = 0; kp < 8; ++kp) {
            float4 v = *reinterpret_cast<const float4*>(q1p + (size_t)kp * 131072 + off);
            a.x += v.x; a.y += v.y; a.z += v.z; a.w += v.w;
        }
        float4 bv = *reinterpret_cast<const float4*>(qb1 + c4);
        float4 r;
        r.x = gelu_exact(a.x + bv.x);
        r.y = gelu_exact(a.y + bv.y);
        r.z = gelu_exact(a.z + bv.z);
        r.w = gelu_exact(a.w + bv.w);
        *reinterpret_cast<float4*>(q1p + off) = r;
    }
}

// K-split x8. blocks 0..255: q out (K=64); 256..767: content out (K=128).
__global__ __launch_bounds__(256) void layer2_kernel(
    const float* __restrict__ q1, const float* __restrict__ qw2, float* __restrict__ q2p,
    const float* __restrict__ h1T, const float* __restrict__ W2, float* __restrict__ c2p,
    const int* __restrict__ chunk_plane, const int* __restrict__ nchunks_p)
{
    int bid = blockIdx.x;
    int tid = threadIdx.x;
    float4 c0 = {0.f,0.f,0.f,0.f}, c1 = {0.f,0.f,0.f,0.f};
    if (bid < 256) {                            // q out
        int kp = bid & 7, tile = bid >> 3;      // 32 tiles
        int rt = tile >> 2, ct = tile & 3;
        int tr = tid >> 4, tc = tid & 15;
        int row = rt * 32 + tr * 2, col = ct * 64 + tc * 4;
        const float* a0 = q1 + (size_t)row * QH_ + kp * 64;
        rgemm_inner(a0, a0 + QH_, qw2 + (size_t)(kp * 64) * QO_ + col, QO_, 64, c0, c1);
        float* o = q2p + (size_t)kp * 65536;
        *reinterpret_cast<float4*>(o + (size_t)row * QO_ + col) = c0;
        *reinterpret_cast<float4*>(o + (size_t)(row + 1) * QO_ + col) = c1;
    } else {                                    // content out
        int b2i = bid - 256;
        int kp = b2i & 7, tile = b2i >> 3;      // 64 tiles
        int c = tile >> 2, jt = tile & 3;
        if (c >= *nchunks_p) return;
        int p = chunk_plane[c];
        int tr = tid >> 3, tc = tid & 7;        // 32 x 8 threads
        int J = jt * 64 + tr * 2;
        int slot = c * 32 + tc * 4;
        const float* a0 = W2 + ((size_t)p * DS_ + J) * DHID_ + kp * 128;
        rgemm_inner(a0, a0 + DHID_, h1T + (size_t)(kp * 128) * SLOTS_ + slot, SLOTS_, 128, c0, c1);
        float* o = c2p + (size_t)kp * 131072;
        *reinterpret_cast<float4*>(o + (size_t)J * SLOTS_ + slot) = c0;
        *reinterpret_cast<float4*>(o + (size_t)(J + 1) * SLOTS_ + slot) = c1;
    }
}

// score: sums q2p/c2p partials in-block (combine2 fused), then softmax/argmax +
// state updates.
__global__ __launch_bounds__(256) void score_kernel(
    const float* __restrict__ keys, const float* __restrict__ q2p,
    const float* __restrict__ c2p, const float* __restrict__ qb2,
    const float* __restrict__ b2,
    const int* __restrict__ slot_of, const int* __restrict__ chunk_plane,
    const int* __restrict__ neighbors,
    int* __restrict__ pos, float* __restrict__ s_out, float* __restrict__ ws_out,
    float* __restrict__ motor_out, float* __restrict__ co_out,
    float* __restrict__ vc_out, float* __restrict__ mp_all, int t)
{
    int w = blockIdx.x;
    int b = w >> 4;
    int tid = threadIdx.x;
    int pold = pos[w];
    int slot = slot_of[w];
    __shared__ float qv_s[256];
    __shared__ int nbr_s[32];
    __shared__ float part_s[8][32];
    __shared__ float sc_s[32];
    if (tid < 32) nbr_s[tid] = neighbors[(size_t)pold * K_ + tid];
    // qv[w][tid] = sum partials + bias
    float qsum = qb2[tid];
#pragma unroll
    for (int kp = 0; kp < 8; ++kp) qsum += q2p[(size_t)kp * 65536 + (size_t)w * QO_ + tid];
    qv_s[tid] = qsum;
    // content[w][tid] = sum partials + bias (column gather from c2p)
    float csum = b2[chunk_plane[slot >> 5] * DS_ + tid];
#pragma unroll
    for (int kp = 0; kp < 8; ++kp) csum += c2p[(size_t)kp * 131072 + (size_t)tid * SLOTS_ + slot];
    __syncthreads();
    int k = tid & 31, part = tid >> 5;
    int nk = nbr_s[k];
    const float* kp_ = keys + (size_t)nk * 256 + part * 32;
    const float* qp = qv_s + part * 32;
    float acc = 0.f;
#pragma unroll
    for (int i = 0; i < 32; i += 4) {
        float4 kv = *reinterpret_cast<const float4*>(kp_ + i);
        acc += kv.x * qp[i] + kv.y * qp[i+1] + kv.z * qp[i+2] + kv.w * qp[i+3];
    }
    part_s[part][k] = acc;
    __syncthreads();
    if (tid < 32) {
        float s = 0.f;
#pragma unroll
        for (int p8 = 0; p8 < 8; ++p8) s += part_s[p8][tid];
        sc_s[tid] = s * SCORE_SCALE;
    }
    __syncthreads();
    if (tid < 32) {
        float sv = sc_s[tid];
        float m = sv;
        for (int off = 1; off < 32; off <<= 1) m = fmaxf(m, __shfl_xor(m, off));
        float e = expf(sv - m);
        float ssum = e;
        for (int off = 1; off < 32; off <<= 1) ssum += __shfl_xor(ssum, off);
        float prob = e / ssum;
        atomicAdd(&mp_all[t * 32 + tid], prob);
        float bs = sv; int bi = tid;
        for (int off = 1; off < 32; off <<= 1) {
            float os = __shfl_xor(bs, off);
            int   oi = __shfl_xor(bi, off);
            if (os > bs || (os == bs && oi < bi)) { bs = os; bi = oi; }
        }
        if (tid == 0) {
            int next = nbr_s[bi];
            pos[w] = next;
            atomicAdd(&co_out[(size_t)pold * N_ + next], 1.0f);
            atomicAdd(&vc_out[next], 1.0f);
        }
    }
    atomicAdd(&s_out[((size_t)b * N_ + pold) * DS_ + tid], csum);
    float wn = ws_out[(size_t)w * DS_ + tid] + csum;
    ws_out[(size_t)w * DS_ + tid] = wn;
    atomicAdd(&motor_out[((size_t)b * T_ + t) * DS_ + tid], wn * (1.0f / H_));
}

__global__ __launch_bounds__(256) void final_kernel(
    const int* __restrict__ pos, const float* __restrict__ mp_all,
    float* __restrict__ pos_out, float* __restrict__ lb_out)
{
    int tid = threadIdx.x;
    pos_out[tid] = (float)pos[tid];
    float v = mp_all[tid] * (1.0f / 256.f);
    v = v * v;
    for (int off = 32; off > 0; off >>= 1) v += __shfl_down(v, off);
    __shared__ float red[4];
    if ((tid & 63) == 0) red[tid >> 6] = v;
    __syncthreads();
    if (tid == 0) lb_out[0] = (float)K_ * (red[0] + red[1] + red[2] + red[3]);
}

// ---------------- launch ----------------

extern "C" void kernel_launch(void* const* d_in, const int* in_sizes, int n_in,
                              void* d_out, int out_size, void* d_ws, size_t ws_size,
                              hipStream_t stream)
{
    const float* s_in      = (const float*)d_in[0];
    const float* node_id   = (const float*)d_in[1];
    const float* wstate_in = (const float*)d_in[2];
    const float* token     = (const float*)d_in[3];
    const float* norm_w    = (const float*)d_in[4];
    const float* W1        = (const float*)d_in[5];
    const float* b1        = (const float*)d_in[6];
    const float* W2        = (const float*)d_in[7];
    const float* b2        = (const float*)d_in[8];
    const float* qw1       = (const float*)d_in[9];
    const float* qb1       = (const float*)d_in[10];
    const float* qw2       = (const float*)d_in[11];
    const float* qb2       = (const float*)d_in[12];
    const float* kw1       = (const float*)d_in[13];
    const float* kb1       = (const float*)d_in[14];
    const float* kw2       = (const float*)d_in[15];
    const float* kb2       = (const float*)d_in[16];
    const int* walker_pos  = (const int*)d_in[17];
    const int* plane_idx   = (const int*)d_in[18];
    const int* neighbors   = (const int*)d_in[19];

    float* out = (float*)d_out;
    float* out_motor = out;                               // B*T*DS   = 32768
    float* out_s     = out_motor + 32768;                 // B*N*DS   = 16777216
    float* out_pos   = out_s + (size_t)16777216;          // B*H      = 256
    float* out_ws    = out_pos + 256;                     // B*H*DS   = 65536
    float* out_co    = out_ws + 65536;                    // N*N      = 16777216
    float* out_vc    = out_co + (size_t)16777216;         // N        = 4096
    float* out_lb    = out_vc + 4096;                     // 1

    // workspace layout (floats). PART region is time-shared:
    //   setup:  kh (4096x512 = 2097152)
    //   layer1: h1p[8][1024][512] at PART; q1p[8][256][512] at PART+4194304
    //   after combine1: h1T = h1p[0]; q1 = q1p[0]
    //   layer2: c2p[8][256][512] at PART+524288 (dead h1p[1..] region);
    //           q2p[8][256][256] at PART+1572864
    float* ws = (float*)d_ws;
    float* keys    = ws;                                  // 1048576
    float* steer   = keys + 1048576;                      // 229376
    float* steerT  = steer + 229376;                      // 896*512 = 458752
    float* PART    = steerT + 458752;                     // 5242880
    float* kh   = PART;
    float* h1p  = PART;
    float* q1p  = PART + 4194304;
    float* h1T  = PART;                                   // alias h1p[0]
    float* q1v  = PART + 4194304;                         // alias q1p[0]
    float* c2p  = PART + 524288;
    float* q2p  = PART + 1572864;
    float* mp_all = PART + 5242880;                       // 256
    int* pos         = (int*)(mp_all + 256);              // 256
    int* plane_order = pos + 256;                         // 2048
    int* chunk_plane = plane_order + 2048;                // 16
    int* chunk_rows  = chunk_plane + 16;                  // 512
    int* slot_of     = chunk_rows + 512;                  // 256
    int* nchunks_p   = slot_of + 256;                     // 1
    // total ~7.0M floats ~= 28 MB

    biginit_kernel<<<4096, 256, 0, stream>>>(s_in, wstate_in, out_motor, out_s,
                                             out_ws, out_co, out_vc, out_lb);
    init_kernel<<<1, 256, 0, stream>>>(walker_pos, plane_idx, pos, mp_all,
                                       plane_order, chunk_plane, chunk_rows,
                                       slot_of, nchunks_p);
    // keys = mlp2(node_id) precomputed for all N nodes (two register GEMMs)
    rgemm_nat_kernel<<<128 * 8, 256, 0, stream>>>(node_id, DID_, kw1, QH_, kb1, kh, 8, 1);
    rgemm_nat_kernel<<<128 * 4, 256, 0, stream>>>(kh, QH_, kw2, QO_, kb2, keys, 4, 0);

    for (int t = 0; t < T_; ++t) {
        steer_kernel<<<256, 256, 0, stream>>>(out_s, node_id, out_ws, token,
                                              norm_w, pos, slot_of, steer, steerT, t);
        layer1_kernel<<<2560, 256, 0, stream>>>(steer, steerT, qw1, q1p,
                                                W1, h1p, chunk_plane, nchunks_p);
        combine1_kernel<<<640, 256, 0, stream>>>(h1p, q1p, b1, qb1, chunk_plane);
        layer2_kernel<<<768, 256, 0, stream>>>(q1v, qw2, q2p, h1T, W2, c2p,
                                               chunk_plane, nchunks_p);
        score_kernel<<<256, 256, 0, stream>>>(keys, q2p, c2p, qb2, b2,
                                              slot_of, chunk_plane, neighbors, pos,
                                              out_s, out_ws, out_motor, out_co,
                                              out_vc, mp_all, t);
    }
    final_kernel<<<1, 256, 0, stream>>>(pos, mp_all, out_pos, out_lb);
}